// Round 1
// baseline (989.500 us; speedup 1.0000x reference)
//
#include <hip/hip_runtime.h>

// ---------- types ----------
using bf16x8 = __attribute__((ext_vector_type(8))) short;
using f32x4  = __attribute__((ext_vector_type(4))) float;
using us4    = __attribute__((ext_vector_type(4))) unsigned short;
using us8    = __attribute__((ext_vector_type(8))) unsigned short;

static __device__ __forceinline__ unsigned short f2bf(float x) {
  union { float f; unsigned u; } v; v.f = x;
  unsigned r = v.u + 0x7FFFu + ((v.u >> 16) & 1u);
  return (unsigned short)(r >> 16);
}
static __device__ __forceinline__ unsigned pack2bf(float a, float b) {
  return (unsigned)f2bf(a) | ((unsigned)f2bf(b) << 16);
}

#define SCALE_ATTN 0.125f

// ---------- f32 -> bf16 convert (n4 = n/4) ----------
__global__ __launch_bounds__(256) void k_cvt(const float* __restrict__ in,
                                             unsigned short* __restrict__ out, int n4) {
  int i = blockIdx.x * 256 + threadIdx.x;
  if (i >= n4) return;
  float4 v = ((const float4*)in)[i];
  us4 o = { f2bf(v.x), f2bf(v.y), f2bf(v.z), f2bf(v.w) };
  ((us4*)out)[i] = o;
}

// ---------- weight transpose: W (K,N) f32 -> Wt (N,K) bf16 ----------
__global__ __launch_bounds__(256) void k_twt(const float* __restrict__ W,
                                             unsigned short* __restrict__ Wt, int K, int N) {
  __shared__ float tile[32][33];
  int nb = blockIdx.x * 32, kb = blockIdx.y * 32;
  int t = threadIdx.x;
  int k = t >> 3, n4 = (t & 7) << 2;
  float4 v = *(const float4*)&W[(size_t)(kb + k) * N + nb + n4];
  tile[k][n4] = v.x; tile[k][n4 + 1] = v.y; tile[k][n4 + 2] = v.z; tile[k][n4 + 3] = v.w;
  __syncthreads();
  int n = t >> 3, k4 = (t & 7) << 2;
  us4 o = { f2bf(tile[k4][n]), f2bf(tile[k4 + 1][n]), f2bf(tile[k4 + 2][n]), f2bf(tile[k4 + 3][n]) };
  *(us4*)&Wt[(size_t)(nb + n) * K + kb + k4] = o;
}

// ---------- GEMM: C = A(M,K)bf16 @ Bt(N,K)bf16^T + bias ----------
// outb: bf16 (M,N); outf: f32 (M,N); outT: bf16 (B,16,64,Lv) for cols>=vt_col0
// A rows per batch = Lr, A batch stride = bsA elems. M = gridDim.x*128.
__global__ __launch_bounds__(256) void k_gemm(
    const unsigned short* __restrict__ A, const unsigned short* __restrict__ Bt,
    const float* __restrict__ bias,
    unsigned short* __restrict__ outb, float* __restrict__ outf,
    unsigned short* __restrict__ outT, int Lv, int vt_col0,
    int N, int K, int Lr, long long bsA) {
  __shared__ unsigned short As[128 * 40];
  __shared__ unsigned short Bs[128 * 40];
  const int m0 = blockIdx.x * 128, n0 = blockIdx.y * 128;
  const int t = threadIdx.x;
  const int w = t >> 6, l = t & 63;
  const int wr = w >> 1, wc = w & 1;
  const int lg = l >> 4, lq = l & 15;
  const int batch = m0 / Lr;
  const unsigned short* Ab = A + (size_t)batch * (size_t)bsA + (size_t)(m0 % Lr) * K;
  const unsigned short* Bb = Bt + (size_t)n0 * K;
  const f32x4 fz = {0.f, 0.f, 0.f, 0.f};
  f32x4 acc[4][4];
#pragma unroll
  for (int i = 0; i < 4; ++i)
#pragma unroll
    for (int j = 0; j < 4; ++j) acc[i][j] = fz;
  const int srow = t >> 2;
  const int sko = (t & 3) << 3;
  for (int k0 = 0; k0 < K; k0 += 32) {
    __syncthreads();
#pragma unroll
    for (int it = 0; it < 2; ++it) {
      int r = srow + it * 64;
      *(bf16x8*)&As[r * 40 + sko] = *(const bf16x8*)&Ab[(size_t)r * K + k0 + sko];
      *(bf16x8*)&Bs[r * 40 + sko] = *(const bf16x8*)&Bb[(size_t)r * K + k0 + sko];
    }
    __syncthreads();
    bf16x8 af[4], bg[4];
#pragma unroll
    for (int i = 0; i < 4; ++i) {
      af[i] = *(const bf16x8*)&As[(wr * 64 + i * 16 + lq) * 40 + lg * 8];
      bg[i] = *(const bf16x8*)&Bs[(wc * 64 + i * 16 + lq) * 40 + lg * 8];
    }
#pragma unroll
    for (int i = 0; i < 4; ++i)
#pragma unroll
      for (int j = 0; j < 4; ++j)
        acc[i][j] = __builtin_amdgcn_mfma_f32_16x16x32_bf16(af[i], bg[j], acc[i][j], 0, 0, 0);
  }
  const int lr = lg << 2;
#pragma unroll
  for (int i = 0; i < 4; ++i) {
    const int rowb = m0 + wr * 64 + i * 16 + lr;
#pragma unroll
    for (int j = 0; j < 4; ++j) {
      const int col = n0 + wc * 64 + j * 16 + lq;
      const float bv = bias[col];
      float v0 = acc[i][j][0] + bv, v1 = acc[i][j][1] + bv;
      float v2 = acc[i][j][2] + bv, v3 = acc[i][j][3] + bv;
      if (outT && col >= vt_col0) {
        const int vc = col - vt_col0;
        const int hh = vc >> 6, dd = vc & 63;
        const int bb = rowb / Lr, key = rowb % Lr;
        us4 o = { f2bf(v0), f2bf(v1), f2bf(v2), f2bf(v3) };
        *(us4*)&outT[((size_t)((bb << 4) + hh) * 64 + dd) * Lv + key] = o;
      } else {
        if (outb) {
          outb[(size_t)(rowb + 0) * N + col] = f2bf(v0);
          outb[(size_t)(rowb + 1) * N + col] = f2bf(v1);
          outb[(size_t)(rowb + 2) * N + col] = f2bf(v2);
          outb[(size_t)(rowb + 3) * N + col] = f2bf(v3);
        }
        if (outf) {
          outf[(size_t)(rowb + 0) * N + col] = v0;
          outf[(size_t)(rowb + 1) * N + col] = v1;
          outf[(size_t)(rowb + 2) * N + col] = v2;
          outf[(size_t)(rowb + 3) * N + col] = v3;
        }
      }
    }
  }
}

// ---------- flash attention ----------
// Q rows at (q_row0+qrow)*q_stride + h*64 ; K rows at key*k_stride + k_col0 + h*64
// VT: (B,16,64,Lk) bf16 ; O: (B,Lq,1024) bf16. causal: mask key > q_row0+qrow.
__global__ __launch_bounds__(256) void k_attn(
    const unsigned short* __restrict__ Q, long long q_bs, int q_stride, int q_row0,
    const unsigned short* __restrict__ Kp, long long k_bs, int k_stride, int k_col0,
    const unsigned short* __restrict__ VT, int Lk,
    unsigned short* __restrict__ O, int Lq, int causal) {
  __shared__ unsigned short Ks[32 * 72];
  __shared__ unsigned short Vs[64 * 40];
  __shared__ unsigned short Ps[4 * 16 * 40];
  const int b = blockIdx.z, h = blockIdx.y;
  const int qblk = blockIdx.x * 64;
  const int t = threadIdx.x, w = t >> 6, l = t & 63;
  const int lg = l >> 4, lq = l & 15;
  const int qrow = qblk + w * 16 + lq;
  const int qidx = q_row0 + qrow;
  const unsigned short* qp = Q + (size_t)b * (size_t)q_bs + (size_t)qidx * q_stride + h * 64;
  bf16x8 qf0 = *(const bf16x8*)&qp[lg * 8];
  bf16x8 qf1 = *(const bf16x8*)&qp[32 + lg * 8];
  const f32x4 fz = {0.f, 0.f, 0.f, 0.f};
  f32x4 acc[4];
#pragma unroll
  for (int i = 0; i < 4; ++i) acc[i] = fz;
  float m = -3e38f, lsum = 0.f;
  const int wqmax = q_row0 + qblk + w * 16 + 15;
  int nkeys = causal ? (q_row0 + qblk + 64) : Lk;
  if (nkeys > Lk) nkeys = Lk;
  const int ntiles = (nkeys + 31) >> 5;
  const int skey = t >> 3, shd = (t & 7) << 3;
  const int svd = t >> 2, svk = (t & 3) << 3;
  const unsigned short* kbp = Kp + (size_t)b * (size_t)k_bs + k_col0 + h * 64;
  const unsigned short* vbp = VT + (size_t)(((b << 4) + h) * 64) * Lk;
  unsigned short* pw = &Ps[(w * 16 + lq) * 40];
  for (int kt = 0; kt < ntiles; ++kt) {
    const int k0 = kt * 32;
    __syncthreads();
    *(bf16x8*)&Ks[skey * 72 + shd] = *(const bf16x8*)&kbp[(size_t)(k0 + skey) * k_stride + shd];
    *(bf16x8*)&Vs[svd * 40 + svk] = *(const bf16x8*)&vbp[(size_t)svd * Lk + k0 + svk];
    __syncthreads();
    if (causal && k0 > wqmax) continue;  // barrier-count stays uniform: next stop is top sync
    float s[2][4];
#pragma unroll
    for (int kh = 0; kh < 2; ++kh) {
      bf16x8 ka = *(const bf16x8*)&Ks[(kh * 16 + lq) * 72 + lg * 8];
      bf16x8 kb = *(const bf16x8*)&Ks[(kh * 16 + lq) * 72 + 32 + lg * 8];
      f32x4 z = fz;
      z = __builtin_amdgcn_mfma_f32_16x16x32_bf16(ka, qf0, z, 0, 0, 0);
      z = __builtin_amdgcn_mfma_f32_16x16x32_bf16(kb, qf1, z, 0, 0, 0);
#pragma unroll
      for (int r = 0; r < 4; ++r) {
        float sv = z[r] * SCALE_ATTN;
        int kg = k0 + kh * 16 + lg * 4 + r;
        if (causal && kg > qidx) sv = -1e9f;
        s[kh][r] = sv;
      }
    }
    float tmax = fmaxf(fmaxf(fmaxf(s[0][0], s[0][1]), fmaxf(s[0][2], s[0][3])),
                       fmaxf(fmaxf(s[1][0], s[1][1]), fmaxf(s[1][2], s[1][3])));
    tmax = fmaxf(tmax, __shfl_xor(tmax, 16));
    tmax = fmaxf(tmax, __shfl_xor(tmax, 32));
    float mnew = fmaxf(m, tmax);
    float corr = __expf(m - mnew);
    float p[2][4], psum = 0.f;
#pragma unroll
    for (int kh = 0; kh < 2; ++kh)
#pragma unroll
      for (int r = 0; r < 4; ++r) { p[kh][r] = __expf(s[kh][r] - mnew); psum += p[kh][r]; }
    psum += __shfl_xor(psum, 16);
    psum += __shfl_xor(psum, 32);
    lsum = lsum * corr + psum;
    m = mnew;
#pragma unroll
    for (int i = 0; i < 4; ++i) acc[i] *= corr;
#pragma unroll
    for (int kh = 0; kh < 2; ++kh) {
      *(unsigned*)&pw[kh * 16 + lg * 4]     = pack2bf(p[kh][0], p[kh][1]);
      *(unsigned*)&pw[kh * 16 + lg * 4 + 2] = pack2bf(p[kh][2], p[kh][3]);
    }
    asm volatile("s_waitcnt lgkmcnt(0)" ::: "memory");
    bf16x8 pf = *(const bf16x8*)&Ps[(w * 16 + lq) * 40 + lg * 8];
#pragma unroll
    for (int mt = 0; mt < 4; ++mt) {
      bf16x8 vf = *(const bf16x8*)&Vs[(mt * 16 + lq) * 40 + lg * 8];
      acc[mt] = __builtin_amdgcn_mfma_f32_16x16x32_bf16(vf, pf, acc[mt], 0, 0, 0);
    }
  }
  float inv = 1.f / lsum;
  size_t ob = ((size_t)b * Lq + qrow) * 1024 + h * 64;
#pragma unroll
  for (int mt = 0; mt < 4; ++mt) {
    us4 o = { f2bf(acc[mt][0] * inv), f2bf(acc[mt][1] * inv),
              f2bf(acc[mt][2] * inv), f2bf(acc[mt][3] * inv) };
    *(us4*)&O[ob + mt * 16 + lg * 4] = o;
  }
}

// ---------- combined = [gctx(256) ; x_chunk(1024)] per batch, bf16 ----------
__global__ __launch_bounds__(256) void k_comb(const unsigned short* __restrict__ gctx,
                                              const unsigned short* __restrict__ xb,
                                              int chunk, unsigned short* __restrict__ comb) {
  int i = blockIdx.x * 256 + threadIdx.x;
  int e = i << 3;
  int b = (e >= 1280 * 1024) ? 1 : 0;
  int rem = e - b * 1280 * 1024;
  int row = rem >> 10, col = rem & 1023;
  us8 v;
  if (row < 256) v = *(const us8*)&gctx[((size_t)b * 256 + row) * 1024 + col];
  else v = *(const us8*)&xb[((size_t)b * 4096 + chunk * 1024 + row - 256) * 1024 + col];
  *(us8*)&comb[e] = v;
}

// ---------- residual: out = lo + x_chunk ; cob = bf16(out) ----------
__global__ __launch_bounds__(256) void k_resid(const float* __restrict__ lo,
                                               const float* __restrict__ x,
                                               int chunk, float* __restrict__ out,
                                               unsigned short* __restrict__ cob) {
  int i = blockIdx.x * 256 + threadIdx.x;
  int e = i << 2;
  int b = (e >= 1024 * 1024) ? 1 : 0;
  int rem = e - b * 1024 * 1024;
  float4 a = *(const float4*)&lo[e];
  size_t xoff = ((size_t)b * 4096 + (size_t)chunk * 1024) * 1024 + rem;
  float4 xv = *(const float4*)&x[xoff];
  float4 r = make_float4(a.x + xv.x, a.y + xv.y, a.z + xv.z, a.w + xv.w);
  *(float4*)&out[xoff] = r;
  us4 o = { f2bf(r.x), f2bf(r.y), f2bf(r.z), f2bf(r.w) };
  *(us4*)&cob[e] = o;
}

extern "C" void kernel_launch(void* const* d_in, const int* in_sizes, int n_in,
                              void* d_out, int out_size, void* d_ws, size_t ws_size,
                              hipStream_t stream) {
  const float* x     = (const float*)d_in[0];
  const float* sq    = (const float*)d_in[1];
  const float* cq_w  = (const float*)d_in[2];
  const float* cq_b  = (const float*)d_in[3];
  const float* ck_w  = (const float*)d_in[4];
  const float* ck_b  = (const float*)d_in[5];
  const float* cv_w  = (const float*)d_in[6];
  const float* cv_b  = (const float*)d_in[7];
  const float* co_w  = (const float*)d_in[8];
  const float* co_b  = (const float*)d_in[9];
  const float* qkv_w = (const float*)d_in[10];
  const float* qkv_b = (const float*)d_in[11];
  const float* lo_w  = (const float*)d_in[12];
  const float* lo_b  = (const float*)d_in[13];
  float* out = (float*)d_out;

  char* ws = (char*)d_ws;
  size_t off = 0;
  auto alloc = [&](size_t bytes) -> void* {
    void* p = ws + off;
    off += (bytes + 255) & ~(size_t)255;
    return p;
  };
  unsigned short* xb    = (unsigned short*)alloc(16777216);   // x bf16 (B,4096,1024)
  unsigned short* sqb   = (unsigned short*)alloc(524288);     // summary queries bf16
  unsigned short* wqt   = (unsigned short*)alloc(2097152);
  unsigned short* wkt   = (unsigned short*)alloc(2097152);
  unsigned short* wvt   = (unsigned short*)alloc(2097152);
  unsigned short* wot   = (unsigned short*)alloc(2097152);
  unsigned short* wqkvt = (unsigned short*)alloc(6291456);
  unsigned short* wlot  = (unsigned short*)alloc(2097152);
  unsigned short* qs    = (unsigned short*)alloc(524288);     // q_summary (256,1024) bf16
  unsigned short* kc    = (unsigned short*)alloc(4194304);    // comp K (B,1024,1024)
  unsigned short* vtc   = (unsigned short*)alloc(4194304);    // comp V^T (B,16,64,1024)
  unsigned short* attc  = (unsigned short*)alloc(1048576);    // comp attn out (B,256,1024)
  unsigned short* gctx  = (unsigned short*)alloc(1048576);    // gctx bf16 (B,256,1024)
  unsigned short* comb  = (unsigned short*)alloc(5242880);    // (B,1280,1024)
  unsigned short* qkv   = (unsigned short*)alloc(15728640);   // (B,1280,3072)
  unsigned short* vtl   = (unsigned short*)alloc(5242880);    // local V^T (B,16,64,1280)
  unsigned short* attl  = (unsigned short*)alloc(4194304);    // local attn out (B,1024,1024)
  float*          lotmp = (float*)alloc(8388608);             // lo proj f32 (B,1024,1024)
  unsigned short* cob   = (unsigned short*)alloc(4194304);    // chunk_out bf16

  // prep
  k_cvt<<<8192, 256, 0, stream>>>(x, xb, 2097152);
  k_cvt<<<256, 256, 0, stream>>>(sq, sqb, 65536);
  k_twt<<<dim3(32, 32), 256, 0, stream>>>(cq_w, wqt, 1024, 1024);
  k_twt<<<dim3(32, 32), 256, 0, stream>>>(ck_w, wkt, 1024, 1024);
  k_twt<<<dim3(32, 32), 256, 0, stream>>>(cv_w, wvt, 1024, 1024);
  k_twt<<<dim3(32, 32), 256, 0, stream>>>(co_w, wot, 1024, 1024);
  k_twt<<<dim3(96, 32), 256, 0, stream>>>(qkv_w, wqkvt, 1024, 3072);
  k_twt<<<dim3(32, 32), 256, 0, stream>>>(lo_w, wlot, 1024, 1024);
  // q_summary = sq @ cq_w + cq_b (batch-invariant, compute once)
  k_gemm<<<dim3(2, 8), 256, 0, stream>>>(sqb, wqt, cq_b, qs, nullptr, nullptr, 0, 0,
                                         1024, 1024, 256, 256LL * 1024);

  auto comp = [&](const unsigned short* inA, long long bsA) {
    k_gemm<<<dim3(16, 8), 256, 0, stream>>>(inA, wkt, ck_b, kc, nullptr, nullptr, 0, 0,
                                            1024, 1024, 1024, bsA);
    k_gemm<<<dim3(16, 8), 256, 0, stream>>>(inA, wvt, cv_b, nullptr, nullptr, vtc, 1024, 0,
                                            1024, 1024, 1024, bsA);
    k_attn<<<dim3(4, 16, 2), 256, 0, stream>>>(qs, 0LL, 1024, 0,
                                               kc, 1024LL * 1024, 1024, 0,
                                               vtc, 1024, attc, 256, 0);
    k_gemm<<<dim3(4, 8), 256, 0, stream>>>(attc, wot, co_b, gctx, nullptr, nullptr, 0, 0,
                                           1024, 1024, 512, 512LL * 1024);
  };

  comp(xb, 4096LL * 1024);  // gctx from raw chunk 0
  for (int i = 0; i < 4; ++i) {
    k_comb<<<1280, 256, 0, stream>>>(gctx, xb, i, comb);
    k_gemm<<<dim3(20, 24), 256, 0, stream>>>(comb, wqkvt, qkv_b, qkv, nullptr, vtl, 1280, 2048,
                                             3072, 1024, 1280, 1280LL * 1024);
    k_attn<<<dim3(16, 16, 2), 256, 0, stream>>>(qkv, 1280LL * 3072, 3072, 256,
                                                qkv, 1280LL * 3072, 3072, 1024,
                                                vtl, 1280, attl, 1024, 1);
    k_gemm<<<dim3(16, 8), 256, 0, stream>>>(attl, wlot, lo_b, nullptr, lotmp, nullptr, 0, 0,
                                            1024, 1024, 2048, 2048LL * 1024);
    k_resid<<<2048, 256, 0, stream>>>(lotmp, x, i, out, cob);
    if (i < 3) comp(cob, 1024LL * 1024);
  }
}

// Round 2
// 739.944 us; speedup vs baseline: 1.3373x; 1.3373x over previous
//
#include <hip/hip_runtime.h>

// ---------- types ----------
using bf16x8 = __attribute__((ext_vector_type(8))) short;
using f32x4  = __attribute__((ext_vector_type(4))) float;
using us4    = __attribute__((ext_vector_type(4))) unsigned short;
using us8    = __attribute__((ext_vector_type(8))) unsigned short;

static __device__ __forceinline__ unsigned short f2bf(float x) {
  union { float f; unsigned u; } v; v.f = x;
  unsigned r = v.u + 0x7FFFu + ((v.u >> 16) & 1u);
  return (unsigned short)(r >> 16);
}
static __device__ __forceinline__ unsigned pack2bf(float a, float b) {
  return (unsigned)f2bf(a) | ((unsigned)f2bf(b) << 16);
}

// async global->LDS, 16B per lane. LDS dest must be wave-uniform base; HW adds lane*16.
static __device__ __forceinline__ void gload16(const unsigned short* g, unsigned short* lds_base) {
  __builtin_amdgcn_global_load_lds(
      (const __attribute__((address_space(1))) unsigned int*)g,
      (__attribute__((address_space(3))) unsigned int*)lds_base, 16, 0, 0);
}

#define SCALE_ATTN 0.125f

// ---------- f32 -> bf16 convert (n4 = n/4) ----------
__global__ __launch_bounds__(256) void k_cvt(const float* __restrict__ in,
                                             unsigned short* __restrict__ out, int n4) {
  int i = blockIdx.x * 256 + threadIdx.x;
  if (i >= n4) return;
  float4 v = ((const float4*)in)[i];
  us4 o = { f2bf(v.x), f2bf(v.y), f2bf(v.z), f2bf(v.w) };
  ((us4*)out)[i] = o;
}

// ---------- weight transpose: W (K,N) f32 -> Wt (N,K) bf16 ----------
__global__ __launch_bounds__(256) void k_twt(const float* __restrict__ W,
                                             unsigned short* __restrict__ Wt, int K, int N) {
  __shared__ float tile[32][33];
  int nb = blockIdx.x * 32, kb = blockIdx.y * 32;
  int t = threadIdx.x;
  int k = t >> 3, n4 = (t & 7) << 2;
  float4 v = *(const float4*)&W[(size_t)(kb + k) * N + nb + n4];
  tile[k][n4] = v.x; tile[k][n4 + 1] = v.y; tile[k][n4 + 2] = v.z; tile[k][n4 + 3] = v.w;
  __syncthreads();
  int n = t >> 3, k4 = (t & 7) << 2;
  us4 o = { f2bf(tile[k4][n]), f2bf(tile[k4 + 1][n]), f2bf(tile[k4 + 2][n]), f2bf(tile[k4 + 3][n]) };
  *(us4*)&Wt[(size_t)(nb + n) * K + kb + k4] = o;
}

// ---------- GEMM: C = A(M,K)bf16 @ Bt(N,K)bf16^T + bias, m97-style staging ----------
// A rows: r < rsplit -> A1[batch*bsA1 + r*K], else A2[batch*bsA2 + (r-rsplit)*K]
// Epilogues: residual (resx!=0): resout=acc+bias+resx, rescob=bf16(same)
//            outT (col>=vt_col0): bf16 transposed (B,16,64,Lv)
//            outb: bf16 row-major stride Nout
__global__ __launch_bounds__(256) void k_gemm(
    const unsigned short* __restrict__ A1, long long bsA1,
    const unsigned short* __restrict__ A2, long long bsA2, int rsplit,
    const unsigned short* __restrict__ Bt, const float* __restrict__ bias,
    unsigned short* __restrict__ outb, int Nout,
    unsigned short* __restrict__ outT, int Lv, int vt_col0,
    const float* __restrict__ resx, float* __restrict__ resout,
    unsigned short* __restrict__ rescob, int chunk,
    int N, int K, int Lr) {
  __shared__ unsigned short As[128 * 32];
  __shared__ unsigned short Bs[128 * 32];
  const int m0 = blockIdx.x * 128, n0 = blockIdx.y * 128;
  const int t = threadIdx.x, w = t >> 6, l = t & 63;
  const int wr = w >> 1, wc = w & 1;
  const int lg = l >> 4, lq = l & 15;
  const int batch = m0 / Lr, mrow = m0 % Lr;
  // staging: lane l of wave w, inst j covers LDS rows (w*2+j)*16 + (l>>2), col (l&3)*8
  const int srow = (l >> 2), scol = (l & 3) * 8;
  const unsigned short* arp[2];
  const unsigned short* brp[2];
#pragma unroll
  for (int j = 0; j < 2; ++j) {
    int r = mrow + (w * 2 + j) * 16 + srow;
    arp[j] = (r < rsplit)
                 ? (A1 + (size_t)batch * (size_t)bsA1 + (size_t)r * K + scol)
                 : (A2 + (size_t)batch * (size_t)bsA2 + (size_t)(r - rsplit) * K + scol);
    int rb = n0 + (w * 2 + j) * 16 + srow;
    brp[j] = Bt + (size_t)rb * K + scol;
  }
  unsigned short* ldsA0 = &As[(w * 2 + 0) * 512];
  unsigned short* ldsA1 = &As[(w * 2 + 1) * 512];
  unsigned short* ldsB0 = &Bs[(w * 2 + 0) * 512];
  unsigned short* ldsB1 = &Bs[(w * 2 + 1) * 512];
  const f32x4 fz = {0.f, 0.f, 0.f, 0.f};
  f32x4 acc[4][4];
#pragma unroll
  for (int i = 0; i < 4; ++i)
#pragma unroll
    for (int j = 0; j < 4; ++j) acc[i][j] = fz;
  for (int k0 = 0; k0 < K; k0 += 32) {
    __syncthreads();
    gload16(arp[0] + k0, ldsA0);
    gload16(arp[1] + k0, ldsA1);
    gload16(brp[0] + k0, ldsB0);
    gload16(brp[1] + k0, ldsB1);
    __syncthreads();
    bf16x8 af[4], bg[4];
#pragma unroll
    for (int i = 0; i < 4; ++i) {
      af[i] = *(const bf16x8*)&As[(wr * 64 + i * 16 + lq) * 32 + lg * 8];
      bg[i] = *(const bf16x8*)&Bs[(wc * 64 + i * 16 + lq) * 32 + lg * 8];
    }
#pragma unroll
    for (int i = 0; i < 4; ++i)
#pragma unroll
      for (int j = 0; j < 4; ++j)
        acc[i][j] = __builtin_amdgcn_mfma_f32_16x16x32_bf16(af[i], bg[j], acc[i][j], 0, 0, 0);
  }
  const int lr = lg << 2;
#pragma unroll
  for (int i = 0; i < 4; ++i) {
    const int rowb = m0 + wr * 64 + i * 16 + lr;
#pragma unroll
    for (int j = 0; j < 4; ++j) {
      const int col = n0 + wc * 64 + j * 16 + lq;
      const float bv = bias[col];
      float v0 = acc[i][j][0] + bv, v1 = acc[i][j][1] + bv;
      float v2 = acc[i][j][2] + bv, v3 = acc[i][j][3] + bv;
      if (resx) {
        const int bb = rowb / Lr, r = rowb % Lr;
        const size_t xo = ((size_t)(bb * 4096 + chunk * 1024 + r)) * 1024 + col;
        const size_t co = ((size_t)(bb * 1024 + r)) * 1024 + col;
        float r0 = v0 + resx[xo];
        float r1 = v1 + resx[xo + 1024];
        float r2 = v2 + resx[xo + 2048];
        float r3 = v3 + resx[xo + 3072];
        resout[xo] = r0; resout[xo + 1024] = r1;
        resout[xo + 2048] = r2; resout[xo + 3072] = r3;
        rescob[co] = f2bf(r0); rescob[co + 1024] = f2bf(r1);
        rescob[co + 2048] = f2bf(r2); rescob[co + 3072] = f2bf(r3);
      } else if (outT && col >= vt_col0) {
        const int vc = col - vt_col0;
        const int hh = vc >> 6, dd = vc & 63;
        const int bb = rowb / Lr, key = rowb % Lr;
        us4 o = { f2bf(v0), f2bf(v1), f2bf(v2), f2bf(v3) };
        *(us4*)&outT[((size_t)((bb << 4) + hh) * 64 + dd) * Lv + key] = o;
      } else {
        outb[(size_t)(rowb + 0) * Nout + col] = f2bf(v0);
        outb[(size_t)(rowb + 1) * Nout + col] = f2bf(v1);
        outb[(size_t)(rowb + 2) * Nout + col] = f2bf(v2);
        outb[(size_t)(rowb + 3) * Nout + col] = f2bf(v3);
      }
    }
  }
}

// ---------- flash attention, KVBLK=64, reg-prefetch next tile ----------
__global__ __launch_bounds__(256) void k_attn(
    const unsigned short* __restrict__ Q, long long q_bs, int q_stride, int q_row0,
    const unsigned short* __restrict__ Kp, long long k_bs, int k_stride, int k_col0,
    const unsigned short* __restrict__ VT, int Lk,
    unsigned short* __restrict__ O, int Lq, int causal) {
  __shared__ unsigned short Ks[64 * 72];
  __shared__ unsigned short Vs[64 * 72];
  __shared__ unsigned short Ps[4 * 16 * 72];
  const int b = blockIdx.z, h = blockIdx.y;
  const int qblk = blockIdx.x * 64;
  const int t = threadIdx.x, w = t >> 6, l = t & 63;
  const int lg = l >> 4, lq = l & 15;
  const int qrow = qblk + w * 16 + lq;
  const int qidx = q_row0 + qrow;
  const unsigned short* qp = Q + (size_t)b * (size_t)q_bs + (size_t)qidx * q_stride + h * 64;
  bf16x8 qf0 = *(const bf16x8*)&qp[lg * 8];
  bf16x8 qf1 = *(const bf16x8*)&qp[32 + lg * 8];
  const f32x4 fz = {0.f, 0.f, 0.f, 0.f};
  f32x4 acc[4];
#pragma unroll
  for (int i = 0; i < 4; ++i) acc[i] = fz;
  float m = -3e38f, lsum = 0.f;
  int nkeys = causal ? (q_row0 + qblk + 64) : Lk;
  if (nkeys > Lk) nkeys = Lk;
  const int ntiles = (nkeys + 63) >> 6;
  const int sr = t >> 2, sc = (t & 3) << 4;  // 64 rows x 32B per thread
  const unsigned short* kbp = Kp + (size_t)b * (size_t)k_bs + k_col0 + h * 64;
  const unsigned short* vbp = VT + (size_t)(((b << 4) + h) * 64) * Lk;
  unsigned short* pw = &Ps[(w * 16 + lq) * 72];
  bf16x8 ka0, ka1, va0, va1;
  {
    const unsigned short* kp = kbp + (size_t)sr * k_stride + sc;
    ka0 = *(const bf16x8*)kp; ka1 = *(const bf16x8*)(kp + 8);
    const unsigned short* vp = vbp + (size_t)sr * Lk + sc;
    va0 = *(const bf16x8*)vp; va1 = *(const bf16x8*)(vp + 8);
  }
  for (int kt = 0; kt < ntiles; ++kt) {
    const int k0 = kt * 64;
    __syncthreads();
    *(bf16x8*)&Ks[sr * 72 + sc] = ka0; *(bf16x8*)&Ks[sr * 72 + sc + 8] = ka1;
    *(bf16x8*)&Vs[sr * 72 + sc] = va0; *(bf16x8*)&Vs[sr * 72 + sc + 8] = va1;
    __syncthreads();
    if (kt + 1 < ntiles) {  // prefetch next tile into regs; latency hides under compute
      const unsigned short* kp = kbp + (size_t)(k0 + 64 + sr) * k_stride + sc;
      ka0 = *(const bf16x8*)kp; ka1 = *(const bf16x8*)(kp + 8);
      const unsigned short* vp = vbp + (size_t)sr * Lk + k0 + 64 + sc;
      va0 = *(const bf16x8*)vp; va1 = *(const bf16x8*)(vp + 8);
    }
    float s[4][4];
#pragma unroll
    for (int kh = 0; kh < 4; ++kh) {
      bf16x8 kaf = *(const bf16x8*)&Ks[(kh * 16 + lq) * 72 + lg * 8];
      bf16x8 kbf = *(const bf16x8*)&Ks[(kh * 16 + lq) * 72 + 32 + lg * 8];
      f32x4 z = fz;
      z = __builtin_amdgcn_mfma_f32_16x16x32_bf16(kaf, qf0, z, 0, 0, 0);
      z = __builtin_amdgcn_mfma_f32_16x16x32_bf16(kbf, qf1, z, 0, 0, 0);
#pragma unroll
      for (int r = 0; r < 4; ++r) {
        float sv = z[r] * SCALE_ATTN;
        int kg = k0 + kh * 16 + lg * 4 + r;
        if (causal && kg > qidx) sv = -1e9f;
        s[kh][r] = sv;
      }
    }
    float tmax = -3e38f;
#pragma unroll
    for (int kh = 0; kh < 4; ++kh)
      tmax = fmaxf(tmax, fmaxf(fmaxf(s[kh][0], s[kh][1]), fmaxf(s[kh][2], s[kh][3])));
    tmax = fmaxf(tmax, __shfl_xor(tmax, 16));
    tmax = fmaxf(tmax, __shfl_xor(tmax, 32));
    float mnew = fmaxf(m, tmax);
    float corr = __expf(m - mnew);
    float p[4][4], psum = 0.f;
#pragma unroll
    for (int kh = 0; kh < 4; ++kh)
#pragma unroll
      for (int r = 0; r < 4; ++r) { p[kh][r] = __expf(s[kh][r] - mnew); psum += p[kh][r]; }
    psum += __shfl_xor(psum, 16);
    psum += __shfl_xor(psum, 32);
    lsum = lsum * corr + psum;
    m = mnew;
#pragma unroll
    for (int i = 0; i < 4; ++i) acc[i] *= corr;
#pragma unroll
    for (int kh = 0; kh < 4; ++kh) {
      *(unsigned*)&pw[kh * 16 + lg * 4]     = pack2bf(p[kh][0], p[kh][1]);
      *(unsigned*)&pw[kh * 16 + lg * 4 + 2] = pack2bf(p[kh][2], p[kh][3]);
    }
    asm volatile("s_waitcnt lgkmcnt(0)" ::: "memory");
    __builtin_amdgcn_sched_barrier(0);
#pragma unroll
    for (int kk = 0; kk < 2; ++kk) {
      bf16x8 pf = *(const bf16x8*)&Ps[(w * 16 + lq) * 72 + kk * 32 + lg * 8];
#pragma unroll
      for (int mt = 0; mt < 4; ++mt) {
        bf16x8 vf = *(const bf16x8*)&Vs[(mt * 16 + lq) * 72 + kk * 32 + lg * 8];
        acc[mt] = __builtin_amdgcn_mfma_f32_16x16x32_bf16(vf, pf, acc[mt], 0, 0, 0);
      }
    }
  }
  float inv = 1.f / lsum;
  size_t ob = ((size_t)b * Lq + qrow) * 1024 + h * 64;
#pragma unroll
  for (int mt = 0; mt < 4; ++mt) {
    us4 o = { f2bf(acc[mt][0] * inv), f2bf(acc[mt][1] * inv),
              f2bf(acc[mt][2] * inv), f2bf(acc[mt][3] * inv) };
    *(us4*)&O[ob + mt * 16 + lg * 4] = o;
  }
}

extern "C" void kernel_launch(void* const* d_in, const int* in_sizes, int n_in,
                              void* d_out, int out_size, void* d_ws, size_t ws_size,
                              hipStream_t stream) {
  const float* x     = (const float*)d_in[0];
  const float* sq    = (const float*)d_in[1];
  const float* cq_w  = (const float*)d_in[2];
  const float* cq_b  = (const float*)d_in[3];
  const float* ck_w  = (const float*)d_in[4];
  const float* ck_b  = (const float*)d_in[5];
  const float* cv_w  = (const float*)d_in[6];
  const float* cv_b  = (const float*)d_in[7];
  const float* co_w  = (const float*)d_in[8];
  const float* co_b  = (const float*)d_in[9];
  const float* qkv_w = (const float*)d_in[10];
  const float* qkv_b = (const float*)d_in[11];
  const float* lo_w  = (const float*)d_in[12];
  const float* lo_b  = (const float*)d_in[13];
  float* out = (float*)d_out;

  char* ws = (char*)d_ws;
  size_t off = 0;
  auto alloc = [&](size_t bytes) -> void* {
    void* p = ws + off;
    off += (bytes + 255) & ~(size_t)255;
    return p;
  };
  unsigned short* xb    = (unsigned short*)alloc(16777216);   // x bf16 (B,4096,1024)
  unsigned short* sqb   = (unsigned short*)alloc(524288);     // summary queries bf16
  unsigned short* wqt   = (unsigned short*)alloc(2097152);
  unsigned short* wkvt  = (unsigned short*)alloc(4194304);    // [ck_w^T ; cv_w^T] (2048,1024)
  unsigned short* wot   = (unsigned short*)alloc(2097152);
  unsigned short* wqkvt = (unsigned short*)alloc(6291456);
  unsigned short* wlot  = (unsigned short*)alloc(2097152);
  float*          kvb   = (float*)alloc(8192);                // [ck_b ; cv_b]
  unsigned short* qs    = (unsigned short*)alloc(524288);     // q_summary (256,1024) bf16
  unsigned short* kc    = (unsigned short*)alloc(4194304);    // comp K (B,1024,1024)
  unsigned short* vtc   = (unsigned short*)alloc(4194304);    // comp V^T (B,16,64,1024)
  unsigned short* attc  = (unsigned short*)alloc(1048576);    // comp attn out (B,256,1024)
  unsigned short* gctx  = (unsigned short*)alloc(1048576);    // gctx bf16 (B,256,1024)
  unsigned short* qkv   = (unsigned short*)alloc(15728640);   // (B,1280,3072) (v cols unused)
  unsigned short* vtl   = (unsigned short*)alloc(5242880);    // local V^T (B,16,64,1280)
  unsigned short* attl  = (unsigned short*)alloc(4194304);    // local attn out (B,1024,1024)
  unsigned short* cob   = (unsigned short*)alloc(4194304);    // chunk_out bf16

  // prep
  k_cvt<<<8192, 256, 0, stream>>>(x, xb, 2097152);
  k_cvt<<<256, 256, 0, stream>>>(sq, sqb, 65536);
  k_twt<<<dim3(32, 32), 256, 0, stream>>>(cq_w, wqt, 1024, 1024);
  k_twt<<<dim3(32, 32), 256, 0, stream>>>(ck_w, wkvt, 1024, 1024);
  k_twt<<<dim3(32, 32), 256, 0, stream>>>(cv_w, wkvt + 1024 * 1024, 1024, 1024);
  k_twt<<<dim3(32, 32), 256, 0, stream>>>(co_w, wot, 1024, 1024);
  k_twt<<<dim3(96, 32), 256, 0, stream>>>(qkv_w, wqkvt, 1024, 3072);
  k_twt<<<dim3(32, 32), 256, 0, stream>>>(lo_w, wlot, 1024, 1024);
  hipMemcpyAsync(kvb, ck_b, 4096, hipMemcpyDeviceToDevice, stream);
  hipMemcpyAsync(kvb + 1024, cv_b, 4096, hipMemcpyDeviceToDevice, stream);
  // q_summary = sq @ cq_w + cq_b (batch-invariant)
  k_gemm<<<dim3(2, 8), 256, 0, stream>>>(nullptr, 0, sqb, 0, 0, wqt, cq_b,
                                         qs, 1024, nullptr, 0, 0,
                                         nullptr, nullptr, nullptr, 0, 1024, 1024, 256);

  auto comp = [&](const unsigned short* inA, long long bsA) {
    // fused K+V projection: N=2048, cols<1024 -> kc, cols>=1024 -> vtc transposed
    k_gemm<<<dim3(16, 16), 256, 0, stream>>>(nullptr, 0, inA, bsA, 0, wkvt, kvb,
                                             kc, 1024, vtc, 1024, 1024,
                                             nullptr, nullptr, nullptr, 0, 2048, 1024, 1024);
    k_attn<<<dim3(4, 16, 2), 256, 0, stream>>>(qs, 0LL, 1024, 0,
                                               kc, 1024LL * 1024, 1024, 0,
                                               vtc, 1024, attc, 256, 0);
    k_gemm<<<dim3(4, 8), 256, 0, stream>>>(nullptr, 0, attc, 0, 0, wot, co_b,
                                           gctx, 1024, nullptr, 0, 0,
                                           nullptr, nullptr, nullptr, 0, 1024, 1024, 512);
  };

  comp(xb, 4096LL * 1024);  // gctx from raw chunk 0
  for (int i = 0; i < 4; ++i) {
    // qkv projection; A rows <256 come from gctx, rest from x chunk i (concat fused)
    k_gemm<<<dim3(20, 24), 256, 0, stream>>>(gctx, 256LL * 1024,
                                             xb + (size_t)i * 1024 * 1024, 4096LL * 1024, 256,
                                             wqkvt, qkv_b,
                                             qkv, 3072, vtl, 1280, 2048,
                                             nullptr, nullptr, nullptr, 0, 3072, 1024, 1280);
    k_attn<<<dim3(16, 16, 2), 256, 0, stream>>>(qkv, 1280LL * 3072, 3072, 256,
                                                qkv, 1280LL * 3072, 3072, 1024,
                                                vtl, 1280, attl, 1024, 1);
    // lo projection with fused residual: out(f32) and cob(bf16)
    k_gemm<<<dim3(16, 8), 256, 0, stream>>>(nullptr, 0, attl, 1024LL * 1024, 0, wlot, lo_b,
                                            nullptr, 1024, nullptr, 0, 0,
                                            x, out, cob, i, 1024, 1024, 1024);
    if (i < 3) comp(cob, 1024LL * 1024);
  }
}